// Round 8
// baseline (37.404 us; speedup 1.0000x reference)
//
#include <hip/hip_runtime.h>

#define TPB    64              // 1 wave per block
#define FPC    30
#define TILE_C 64              // cells per tile
#define TILE_F (TILE_C * FPC)  // 1920 floats = 7680 B per input per tile
#define TILES  4               // tiles per block, double-buffered

typedef const __attribute__((address_space(1))) void* gptr_t;
typedef __attribute__((address_space(3))) void* lptr_t;

// 8 DMA chunks of 1 KiB per input; chunk 7 starts at float 1664 (byte 6656)
// so it ends exactly at 7680 B (512 B overlap with chunk 6, identical data).
__device__ __forceinline__ void stage_tile(const float* __restrict__ bsrc,
                                           const float* __restrict__ gsrc,
                                           float* dB, float* dG, int lane) {
#pragma unroll
    for (int c = 0; c < 8; ++c) {
        const int of = (c < 7) ? c * 256 : 1664;
        __builtin_amdgcn_global_load_lds((gptr_t)(bsrc + of + lane * 4),
                                         (lptr_t)(dB + of), 16, 0, 0);
        __builtin_amdgcn_global_load_lds((gptr_t)(gsrc + of + lane * 4),
                                         (lptr_t)(dG + of), 16, 0, 0);
    }
}

__device__ __forceinline__ void do_cell(const float* __restrict__ Bp,
                                        const float* __restrict__ Gp,
                                        int cell, float* acc) {
    const int w = cell % 49;
    const float gx = (float)(w % 7) * 64.0f;
    const float gy = (float)(w / 7) * 64.0f;

    const float g0 = Gp[5], g1 = Gp[6], g2 = Gp[7], g3 = Gp[8];
    const float g_area = (g2 - g0) * (g3 - g1);

    const float b1x = Bp[0], b1y = Bp[1], b1w = Bp[2], b1h = Bp[3], b1c = Bp[4];
    const float b2x = Bp[5], b2y = Bp[6], b2w = Bp[7], b2h = Bp[8], b2c = Bp[9];

    auto iou_of = [&](float bx, float by, float bw, float bh) -> float {
        float px = truncf(gx + bx * 64.0f);
        float py = truncf(gy + by * 64.0f);
        float pw = truncf(bw * 448.0f);
        float ph = truncf(bh * 448.0f);
        float x1 = fmaxf(0.0f,   px - pw * 0.5f);
        float y1 = fmaxf(0.0f,   py - ph * 0.5f);
        float x2 = fminf(447.0f, px + pw * 0.5f);
        float y2 = fminf(447.0f, py + ph * 0.5f);
        float parea = (x2 - x1) * (y2 - y1);
        float lx = fmaxf(x1, g0), rx = fminf(x2, g2);
        float uy = fmaxf(y1, g1), dn = fminf(y2, g3);
        float inter = (rx - lx) * (dn - uy);
        float denom = parea + g_area - inter;
        denom = (denom == 0.0f) ? 1.0f : denom;
        return ((rx >= lx) && (dn >= uy)) ? (inter / denom) : 0.0f;
    };

    const float iou1 = iou_of(b1x, b1y, b1w, b1h);
    const float iou2 = iou_of(b2x, b2y, b2w, b2h);
    const bool  p1   = iou1 > iou2;

    const float pbx = p1 ? b1x : b2x, pby = p1 ? b1y : b2y;
    const float pbw = p1 ? b1w : b2w, pbh = p1 ? b1h : b2h;
    const float pbc = p1 ? b1c : b2c;
    const float npc = p1 ? b2c : b1c;
    const float iousel = p1 ? iou1 : iou2;

    const bool obj = (rintf(Gp[9]) != 0.0f);   // jnp.round: half-to-even

    const float dx = Gp[0] - pbx;
    const float dy = Gp[1] - pby;
    const float dw = sqrtf(Gp[2] + 1e-8f) - sqrtf(pbw + 1e-8f);
    const float dh = sqrtf(Gp[3] + 1e-8f) - sqrtf(pbh + 1e-8f);
    const float coord = 5.0f * (dx * dx + dy * dy + dw * dw + dh * dh);

    float confobj = pbc - iousel;
    confobj *= confobj;

    float cls = 0.f;
#pragma unroll
    for (int k = 0; k < 20; ++k) {
        float d = Gp[10 + k] - Bp[10 + k];
        cls += d * d;
    }
    cls *= (1.0f / 20.0f);

    const float noobj_of_obj = 0.5f * npc * npc;
    const float objloss   = coord + confobj + cls + noobj_of_obj;
    const float noobjloss = 0.5f * b1c * b1c + b2c * b2c;

    if (obj) {
        acc[0] += objloss; acc[1] += coord; acc[2] += confobj + npc * npc;
        acc[3] += cls;     acc[4] += iousel; acc[5] += 1.0f;
    } else {
        acc[0] += noobjloss; acc[2] += noobjloss;
    }
}

__launch_bounds__(TPB)
__global__ void yolo_loss_kernel(const float* __restrict__ bb,
                                 const float* __restrict__ gt,
                                 float* __restrict__ ws,
                                 int nblocks) {
    __shared__ float sBB[2][TILE_F];
    __shared__ float sGT[2][TILE_F];

    const int lane = threadIdx.x;
    const int bid  = blockIdx.x;

    const size_t baseF   = (size_t)bid * TILES * TILE_F;
    const int    cell0   = bid * TILES * TILE_C + lane;
    const float* __restrict__ bbase = bb + baseF;
    const float* __restrict__ gbase = gt + baseF;

    float acc[6] = {0.f, 0.f, 0.f, 0.f, 0.f, 0.f};

    // Prologue: stage tile 0 into buf 0.
    stage_tile(bbase, gbase, sBB[0], sGT[0], lane);

    // Pipelined steps: stage t+1 into the other buffer, wait for tile t's 16
    // DMAs (counted vmcnt, never 0 until the last tile), compute tile t.
    // Single wave -> no s_barrier needed; "memory" clobber + sched_barrier
    // keep LDS reads below the wait.
#define STEP(T, WAITN_STR)                                                     \
    do {                                                                       \
        if ((T) + 1 < TILES)                                                   \
            stage_tile(bbase + ((T) + 1) * TILE_F, gbase + ((T) + 1) * TILE_F, \
                       sBB[((T) + 1) & 1], sGT[((T) + 1) & 1], lane);          \
        asm volatile("s_waitcnt vmcnt(" WAITN_STR ")" ::: "memory");           \
        __builtin_amdgcn_sched_barrier(0);                                     \
        do_cell(&sBB[(T) & 1][lane * FPC], &sGT[(T) & 1][lane * FPC],          \
                cell0 + (T) * TILE_C, acc);                                    \
    } while (0)

    STEP(0, "16");
    STEP(1, "16");
    STEP(2, "16");
    STEP(3, "0");
#undef STEP

    // ---- Single-wave reduction: shuffle only, lane0 stores 6 partials ------
#pragma unroll
    for (int k = 0; k < 6; ++k) {
#pragma unroll
        for (int off = 32; off > 0; off >>= 1)
            acc[k] += __shfl_down(acc[k], off, 64);
    }
    if (lane == 0) {
#pragma unroll
        for (int k = 0; k < 6; ++k)
            ws[(size_t)k * nblocks + bid] = acc[k];
    }
}

// Second stage: 6 blocks x 1024 threads, float4 loads (nblocks % 4 == 0).
__global__ void reduce_partials(const float* __restrict__ ws,
                                float* __restrict__ out, int nblocks) {
    __shared__ float sw[16];
    const int k   = blockIdx.x;
    const int tid = threadIdx.x;
    const float4* __restrict__ w4 = (const float4*)(ws + (size_t)k * nblocks);
    const int nf4 = nblocks >> 2;

    float s = 0.f;
    for (int i = tid; i < nf4; i += blockDim.x) {
        float4 q = w4[i];
        s += (q.x + q.y) + (q.z + q.w);
    }
#pragma unroll
    for (int off = 32; off > 0; off >>= 1)
        s += __shfl_down(s, off, 64);
    if ((tid & 63) == 0) sw[tid >> 6] = s;
    __syncthreads();
    if (tid == 0) {
        float t = 0.f;
#pragma unroll
        for (int j = 0; j < 16; ++j) t += sw[j];
        out[k] = t;
    }
}

extern "C" void kernel_launch(void* const* d_in, const int* in_sizes, int n_in,
                              void* d_out, int out_size, void* d_ws, size_t ws_size,
                              hipStream_t stream) {
    const float* bb = (const float*)d_in[0];
    const float* gt = (const float*)d_in[1];
    float* out = (float*)d_out;
    float* ws  = (float*)d_ws;

    const int ncells = in_sizes[0] / FPC;          // 802816
    const int grid   = ncells / (TILES * TILE_C);  // 3136 (exact)

    yolo_loss_kernel<<<grid, TPB, 0, stream>>>(bb, gt, ws, grid);
    reduce_partials<<<6, 1024, 0, stream>>>(ws, out, grid);
}

// Round 9
// 35.946 us; speedup vs baseline: 1.0406x; 1.0406x over previous
//
#include <hip/hip_runtime.h>

#define TPB    64              // 1 wave per block
#define CELLS  64              // 1 cell per thread
#define FPC    30
#define TILE_F (CELLS * FPC)   // 1920 floats = 7680 B per input per tile

typedef const __attribute__((address_space(1))) void* gptr_t;
typedef __attribute__((address_space(3))) void* lptr_t;

// 8 DMA chunks of 1 KiB per input; chunk 7 starts at byte 6656 so it ends
// exactly at 7680 (overlaps chunk 6 by 512 B with identical data -> safe,
// and never reads past the tile / array end).

__launch_bounds__(TPB)
__global__ void yolo_loss_kernel(const float* __restrict__ bb,
                                 const float* __restrict__ gt,
                                 float* __restrict__ ws,
                                 int nblocks) {
    __shared__ float sBB[TILE_F];
    __shared__ float sGT[TILE_F];

    const int tid = threadIdx.x;          // == lane (single wave)
    const int bid = blockIdx.x;

    const float* __restrict__ bsrc = bb + (size_t)bid * TILE_F;
    const float* __restrict__ gsrc = gt + (size_t)bid * TILE_F;

#pragma unroll
    for (int c = 0; c < 8; ++c) {
        const int of = (c < 7) ? c * 256 : 1664;     // float offset of chunk
        __builtin_amdgcn_global_load_lds((gptr_t)(bsrc + of + tid * 4),
                                         (lptr_t)(&sBB[of]), 16, 0, 0);
        __builtin_amdgcn_global_load_lds((gptr_t)(gsrc + of + tid * 4),
                                         (lptr_t)(&sGT[of]), 16, 0, 0);
    }
    __syncthreads();   // vmcnt(0) drain; 16 chunks were in flight

    // ---- Per-cell compute --------------------------------------------------
    const float* __restrict__ Bp = &sBB[tid * FPC];
    const float* __restrict__ Gp = &sGT[tid * FPC];

    const int cell = bid * CELLS + tid;
    const int w = cell % 49;
    const float gx = (float)(w % 7) * 64.0f;
    const float gy = (float)(w / 7) * 64.0f;

    const float g0 = Gp[5], g1 = Gp[6], g2 = Gp[7], g3 = Gp[8];
    const float g_area = (g2 - g0) * (g3 - g1);

    const float b1x = Bp[0], b1y = Bp[1], b1w = Bp[2], b1h = Bp[3], b1c = Bp[4];
    const float b2x = Bp[5], b2y = Bp[6], b2w = Bp[7], b2h = Bp[8], b2c = Bp[9];

    auto iou_of = [&](float bx, float by, float bw, float bh) -> float {
        float px = truncf(gx + bx * 64.0f);
        float py = truncf(gy + by * 64.0f);
        float pw = truncf(bw * 448.0f);
        float ph = truncf(bh * 448.0f);
        float x1 = fmaxf(0.0f,   px - pw * 0.5f);
        float y1 = fmaxf(0.0f,   py - ph * 0.5f);
        float x2 = fminf(447.0f, px + pw * 0.5f);
        float y2 = fminf(447.0f, py + ph * 0.5f);
        float parea = (x2 - x1) * (y2 - y1);
        float lx = fmaxf(x1, g0), rx = fminf(x2, g2);
        float uy = fmaxf(y1, g1), dn = fminf(y2, g3);
        float inter = (rx - lx) * (dn - uy);
        float denom = parea + g_area - inter;
        denom = (denom == 0.0f) ? 1.0f : denom;
        return ((rx >= lx) && (dn >= uy)) ? (inter / denom) : 0.0f;
    };

    const float iou1 = iou_of(b1x, b1y, b1w, b1h);
    const float iou2 = iou_of(b2x, b2y, b2w, b2h);
    const bool  p1   = iou1 > iou2;

    const float pbx = p1 ? b1x : b2x, pby = p1 ? b1y : b2y;
    const float pbw = p1 ? b1w : b2w, pbh = p1 ? b1h : b2h;
    const float pbc = p1 ? b1c : b2c;
    const float npc = p1 ? b2c : b1c;
    const float iousel = p1 ? iou1 : iou2;

    const bool obj = (rintf(Gp[9]) != 0.0f);   // jnp.round: half-to-even

    const float dx = Gp[0] - pbx;
    const float dy = Gp[1] - pby;
    const float dw = sqrtf(Gp[2] + 1e-8f) - sqrtf(pbw + 1e-8f);
    const float dh = sqrtf(Gp[3] + 1e-8f) - sqrtf(pbh + 1e-8f);
    const float coord = 5.0f * (dx * dx + dy * dy + dw * dw + dh * dh);

    float confobj = pbc - iousel;
    confobj *= confobj;

    float cls = 0.f;
#pragma unroll
    for (int k = 0; k < 20; ++k) {
        float d = Gp[10 + k] - Bp[10 + k];
        cls += d * d;
    }
    cls *= (1.0f / 20.0f);

    const float noobj_of_obj = 0.5f * npc * npc;
    const float objloss   = coord + confobj + cls + noobj_of_obj;
    const float noobjloss = 0.5f * b1c * b1c + b2c * b2c;

    float L, Lc, Lconf, Lcls, Isum, On;
    if (obj) {
        L = objloss; Lc = coord; Lconf = confobj + npc * npc;
        Lcls = cls;  Isum = iousel; On = 1.0f;
    } else {
        L = noobjloss; Lc = 0.f; Lconf = noobjloss; Lcls = 0.f; Isum = 0.f; On = 0.f;
    }

    // ---- Single-wave reduction: shuffle only, lane0 stores 6 partials ------
    float v[6] = {L, Lc, Lconf, Lcls, Isum, On};
#pragma unroll
    for (int k = 0; k < 6; ++k) {
#pragma unroll
        for (int off = 32; off > 0; off >>= 1)
            v[k] += __shfl_down(v[k], off, 64);
    }
    if (tid == 0) {
#pragma unroll
        for (int k = 0; k < 6; ++k)
            ws[(size_t)k * nblocks + bid] = v[k];
    }
}

// Second stage: 6 blocks x 1024 threads, float4 loads (nblocks % 4 == 0).
__global__ void reduce_partials(const float* __restrict__ ws,
                                float* __restrict__ out, int nblocks) {
    __shared__ float sw[16];
    const int k   = blockIdx.x;
    const int tid = threadIdx.x;
    const float4* __restrict__ w4 = (const float4*)(ws + (size_t)k * nblocks);
    const int nf4 = nblocks >> 2;                 // 12544/4 = 3136

    float s = 0.f;
    for (int i = tid; i < nf4; i += blockDim.x) {
        float4 q = w4[i];
        s += (q.x + q.y) + (q.z + q.w);
    }
#pragma unroll
    for (int off = 32; off > 0; off >>= 1)
        s += __shfl_down(s, off, 64);
    if ((tid & 63) == 0) sw[tid >> 6] = s;
    __syncthreads();
    if (tid == 0) {
        float t = 0.f;
#pragma unroll
        for (int j = 0; j < 16; ++j) t += sw[j];
        out[k] = t;
    }
}

extern "C" void kernel_launch(void* const* d_in, const int* in_sizes, int n_in,
                              void* d_out, int out_size, void* d_ws, size_t ws_size,
                              hipStream_t stream) {
    const float* bb = (const float*)d_in[0];
    const float* gt = (const float*)d_in[1];
    float* out = (float*)d_out;
    float* ws  = (float*)d_ws;

    const int ncells = in_sizes[0] / FPC;   // 802816
    const int grid   = ncells / CELLS;      // 12544 (exact)

    yolo_loss_kernel<<<grid, TPB, 0, stream>>>(bb, gt, ws, grid);
    reduce_partials<<<6, 1024, 0, stream>>>(ws, out, grid);
}